// Round 6
// baseline (171.127 us; speedup 1.0000x reference)
//
#include <hip/hip_runtime.h>
#include <hip/hip_bf16.h>
#include <math.h>

#define N_NODES 2048
#define F_DIM   128
#define H_HEADS 4
#define B_BATCH 8
#define LEAKY   0.2f

typedef float f32x4 __attribute__((ext_vector_type(4)));
typedef float f32x2 __attribute__((ext_vector_type(2)));

__device__ __forceinline__ float tanh_fast(float x) {
    const float e = __expf(2.0f * x);
    return 1.0f - 2.0f / (e + 1.0f);
}

__device__ __forceinline__ void gload_lds16(const void* g, void* l) {
    __builtin_amdgcn_global_load_lds(
        (const __attribute__((address_space(1))) void*)g,
        (__attribute__((address_space(3))) void*)l, 16, 0, 0);
}

// ---------------- Kernel 0: bitpack A (134 MB -> 4 MB) ----------------
// Cached loads: A fits the 256 MB L3 and persists across launches.
__global__ __launch_bounds__(256) void gat_bitpack(const float* __restrict__ A,
                                                   unsigned char* __restrict__ maskb) {
    const int row = blockIdx.x;
    const int tid = threadIdx.x;
    const f32x4* Ar = (const f32x4*)(A + (size_t)row * N_NODES);
    const f32x4 a0 = Ar[tid * 2];
    const f32x4 a1 = Ar[tid * 2 + 1];
    unsigned b = 0;
    b |= (a0.x != 0.0f ? 1u : 0u) << 0;
    b |= (a0.y != 0.0f ? 1u : 0u) << 1;
    b |= (a0.z != 0.0f ? 1u : 0u) << 2;
    b |= (a0.w != 0.0f ? 1u : 0u) << 3;
    b |= (a1.x != 0.0f ? 1u : 0u) << 4;
    b |= (a1.y != 0.0f ? 1u : 0u) << 5;
    b |= (a1.z != 0.0f ? 1u : 0u) << 6;
    b |= (a1.w != 0.0f ? 1u : 0u) << 7;
    maskb[(size_t)row * 256 + tid] = (unsigned char)b;
}

// ---------------- Kernel 1: projections, packed [b][n][h] ----------------
__global__ __launch_bounds__(256) void gat_proj(const float* __restrict__ X,
                                                const float* __restrict__ wS,
                                                const float* __restrict__ wN,
                                                float* __restrict__ aSt,
                                                float* __restrict__ aNt) {
    const int wave = threadIdx.x >> 6;
    const int lane = threadIdx.x & 63;
    const int row  = blockIdx.x * 4 + wave;            // b*N + n
    const float* xr = X + (size_t)row * F_DIM;
    const float x0 = xr[lane];
    const float x1 = xr[lane + 64];
    float4 ps4, pn4;
    float* psv = (float*)&ps4;
    float* pnv = (float*)&pn4;
#pragma unroll
    for (int h = 0; h < H_HEADS; ++h) {
        float ps = x0 * wS[h * F_DIM + lane] + x1 * wS[h * F_DIM + 64 + lane];
        float pn = x0 * wN[h * F_DIM + lane] + x1 * wN[h * F_DIM + 64 + lane];
#pragma unroll
        for (int off = 32; off > 0; off >>= 1) {
            ps += __shfl_xor(ps, off);
            pn += __shfl_xor(pn, off);
        }
        psv[h] = ps;
        pnv[h] = pn;
    }
    if (lane == 0) {
        ((float4*)aSt)[row] = ps4;
        ((float4*)aNt)[row] = pn4;
    }
}

// ---------------- Kernel 1b: per-(b,h) global max of a_neigh ----------------
__global__ __launch_bounds__(256) void gat_gmax(const float* __restrict__ aNt,
                                                float* __restrict__ gmax) {
    const int b = blockIdx.x;
    const int tid = threadIdx.x;
    const int lane = tid & 63;
    const int wv = tid >> 6;
    __shared__ float4 s_part[4];
    float4 m = make_float4(-1e30f, -1e30f, -1e30f, -1e30f);
    const float4* src = (const float4*)aNt + (size_t)b * N_NODES;
    for (int n = tid; n < N_NODES; n += 256) {
        const float4 v = src[n];
        m.x = fmaxf(m.x, v.x); m.y = fmaxf(m.y, v.y);
        m.z = fmaxf(m.z, v.z); m.w = fmaxf(m.w, v.w);
    }
#pragma unroll
    for (int off = 32; off > 0; off >>= 1) {
        m.x = fmaxf(m.x, __shfl_xor(m.x, off));
        m.y = fmaxf(m.y, __shfl_xor(m.y, off));
        m.z = fmaxf(m.z, __shfl_xor(m.z, off));
        m.w = fmaxf(m.w, __shfl_xor(m.w, off));
    }
    if (lane == 0) s_part[wv] = m;
    __syncthreads();
    if (tid == 0) {
        float4 r = s_part[0];
#pragma unroll
        for (int w = 1; w < 4; ++w) {
            r.x = fmaxf(r.x, s_part[w].x); r.y = fmaxf(r.y, s_part[w].y);
            r.z = fmaxf(r.z, s_part[w].z); r.w = fmaxf(r.w, s_part[w].w);
        }
        ((float4*)gmax)[b] = r;
    }
}

// 16-FMA microtile: 4 heads x 4 feature floats
#define FMA16(PV, XV)                                        \
    do {                                                     \
        acc[0][0] = fmaf((PV).x, (XV).x, acc[0][0]);         \
        acc[0][1] = fmaf((PV).x, (XV).y, acc[0][1]);         \
        acc[0][2] = fmaf((PV).x, (XV).z, acc[0][2]);         \
        acc[0][3] = fmaf((PV).x, (XV).w, acc[0][3]);         \
        acc[1][0] = fmaf((PV).y, (XV).x, acc[1][0]);         \
        acc[1][1] = fmaf((PV).y, (XV).y, acc[1][1]);         \
        acc[1][2] = fmaf((PV).y, (XV).z, acc[1][2]);         \
        acc[1][3] = fmaf((PV).y, (XV).w, acc[1][3]);         \
        acc[2][0] = fmaf((PV).z, (XV).x, acc[2][0]);         \
        acc[2][1] = fmaf((PV).z, (XV).y, acc[2][1]);         \
        acc[2][2] = fmaf((PV).z, (XV).z, acc[2][2]);         \
        acc[2][3] = fmaf((PV).z, (XV).w, acc[2][3]);         \
        acc[3][0] = fmaf((PV).w, (XV).x, acc[3][0]);         \
        acc[3][1] = fmaf((PV).w, (XV).y, acc[3][1]);         \
        acc[3][2] = fmaf((PV).w, (XV).z, acc[3][2]);         \
        acc[3][3] = fmaf((PV).w, (XV).w, acc[3][3]);         \
    } while (0)

// ---------------- Kernel 2: sparse softmax-gather per (b,n) row ----------------
// X-gather staged through LDS via global_load_lds, double-buffered 32-row stages.
__global__ __launch_bounds__(256, 3) void gat_main(const float* __restrict__ X,
                                                   const unsigned* __restrict__ maskw,
                                                   const float* __restrict__ aSt,
                                                   const float* __restrict__ aNt,
                                                   const float* __restrict__ gmax,
                                                   float* __restrict__ out) {
    const int tid = threadIdx.x;
    // batch-per-XCD swizzle: XCD k runs exactly batch k (keeps X_b L2-resident).
    const int bid = blockIdx.x;
    const int row = ((bid & 7) << 11) | (bid >> 3);   // b*N + n
    const int b = row >> 11;
    const int lane = tid & 63;
    const int wv = tid >> 6;

    __shared__ short  s_idx[N_NODES];           // compacted neighbor indices (sorted)
    __shared__ float4 s_p4[256];                // p for current chunk: [entry][head]
    __shared__ float4 s_stage4[2 * 32 * 32];    // 2 x (32 rows x 512 B) X stage
    __shared__ float  s_M[4];
    __shared__ float  s_sv[4];
    __shared__ float  s_scr[16];                // [wv][h] lsum partials
    __shared__ int    s_cnt;
    float* s_red = (float*)s_stage4;            // 8 KB overlay, used in phase 3 only

    // ---- Phase 1: popcount-scan of 64 mask dwords (wave 0 only) ----
    unsigned mw = 0;
    if (tid < 64) mw = maskw[(size_t)row * 64 + tid];

    if (tid >= 64 && tid < 68) {                // per-head constants on wave 1
        const int t = tid - 64;
        const float sv = aSt[(size_t)row * 4 + t];
        const float g = gmax[b * 4 + t];
        float v = sv + g;
        v = fmaxf(v, LEAKY * v);                // leaky, monotonic -> valid upper bound
        s_M[t] = v;
        s_sv[t] = sv;
    }

    if (tid < 64) {
        const int c = __popc(mw);
        int incl = c;
#pragma unroll
        for (int d = 1; d < 64; d <<= 1) {
            const int u = __shfl_up(incl, d);
            if (lane >= d) incl += u;
        }
        if (lane == 63) s_cnt = incl;
        int p = incl - c;                       // exclusive prefix
        unsigned m = mw;
        while (m) {
            const int bpos = __ffs(m) - 1;
            s_idx[p++] = (short)((lane << 5) + bpos);
            m &= m - 1;
        }
    }
    __syncthreads();
    const int cnt = s_cnt;

    // hoist per-head constants into registers
    const float rsv[4] = {s_sv[0], s_sv[1], s_sv[2], s_sv[3]};
    const float rM[4]  = {s_M[0], s_M[1], s_M[2], s_M[3]};

    // ---- Phase 2: staged gather-accumulate ----
    float acc[4][4];
#pragma unroll
    for (int h = 0; h < 4; ++h)
#pragma unroll
        for (int fi = 0; fi < 4; ++fi) acc[h][fi] = 0.0f;
    float lsum[4] = {0.0f, 0.0f, 0.0f, 0.0f};

    const int jsub = tid >> 5;                  // 0..7
    const int f4 = tid & 31;                    // 0..31
    const char* XbRow = (const char*)(X + (size_t)b * N_NODES * F_DIM);
    const float4* aNb4 = (const float4*)aNt + (size_t)b * N_NODES;

    // issue the 4 global_load_lds (16 B each) for stage g: rows [g*32, g*32+32)
    // LDS dest: wave-uniform base + lane*16 (hardware); rows 2q,2q+1 per 1 KB issue.
    auto ISSUE = [&](int g) {
        const int so = g << 5;
        const int l5 = lane >> 5;               // 0/1: which of the two rows
        const int c16 = (lane & 31) << 4;       // byte column within row
        char* lb = ((char*)s_stage4) + ((g & 1) << 14) + (wv << 12);
#pragma unroll
        for (int k = 0; k < 4; ++k) {
            const int q = (wv << 2) + k;        // 0..15: 1 KB sub-block
            const int r = so + (q << 1) + l5;   // global entry index (may be pad)
            const int m = ((int)s_idx[r & (N_NODES - 1)]) & (N_NODES - 1);
            const char* gp = XbRow + ((unsigned)m << 9) + c16;
            gload_lds16(gp, lb + (k << 10));
        }
    };

    // p-generation for chunk c (256 entries; zero-fill beyond cnt for padding)
    auto PGEN = [&](int c) {
        const int gidx = (c << 8) + tid;
        float4 p4 = make_float4(0.0f, 0.0f, 0.0f, 0.0f);
        if (gidx < cnt) {
            const int m = s_idx[gidx];
            const float4 t = aNb4[m];
            const float tv[4] = {t.x, t.y, t.z, t.w};
            float* pp = (float*)&p4;
#pragma unroll
            for (int h = 0; h < H_HEADS; ++h) {
                float v = rsv[h] + tv[h];
                v = fmaxf(v, LEAKY * v);
                const float p = __expf(v - rM[h]);
                pp[h] = p;
                lsum[h] += p;
            }
        }
        s_p4[tid] = p4;
    };

    const int NST = (cnt + 31) >> 5;            // number of 32-row stages

    ISSUE(0);                                   // stage-0 loads in flight
    PGEN(0);                                    // overlaps stage-0 latency

    for (int gs = 0; gs < NST; ++gs) {
        const bool more = (gs + 1) < NST;
        if (gs && ((gs & 7) == 0)) PGEN(gs >> 3);   // next chunk's p (s_p4 free)
        if (more) ISSUE(gs + 1);                    // prefetch next stage
        // wait: stage gs (oldest 4 vmem ops) landed in LDS; newest 4 stay in flight.
        if (more) { asm volatile("s_waitcnt vmcnt(4) lgkmcnt(0)" ::: "memory"); }
        else      { asm volatile("s_waitcnt vmcnt(0) lgkmcnt(0)" ::: "memory"); }
        __builtin_amdgcn_s_barrier();
        __builtin_amdgcn_sched_barrier(0);
        {
            const float* buf = (const float*)s_stage4 + ((gs & 1) * (32 * 128));
            const int jb = (gs & 7) << 5;       // p-index base within chunk
#pragma unroll
            for (int k = 0; k < 4; ++k) {
                const int sr = jsub + (k << 3); // 0..31 row within stage
                const float4 pv = *(const float4*)&s_p4[jb + sr];
                const float4 xv = *(const float4*)(buf + sr * 128 + (f4 << 2));
                FMA16(pv, xv);
            }
        }
        __builtin_amdgcn_sched_barrier(0);
        __builtin_amdgcn_s_barrier();           // buf[gs&1] now safe to overwrite
    }

    // ---- Phase 3: reductions + output ----
#pragma unroll
    for (int h = 0; h < H_HEADS; ++h) {
        float v = lsum[h];
#pragma unroll
        for (int off = 32; off > 0; off >>= 1) v += __shfl_xor(v, off);
        if (lane == 0) s_scr[wv * 4 + h] = v;
    }
#pragma unroll
    for (int h = 0; h < 4; ++h)
#pragma unroll
        for (int fi = 0; fi < 4; ++fi)
            acc[h][fi] += __shfl_xor(acc[h][fi], 32);
    if (lane < 32) {
        float4* red4 = (float4*)s_red;
#pragma unroll
        for (int h = 0; h < 4; ++h)
            red4[wv * 128 + h * 32 + f4] =
                make_float4(acc[h][0], acc[h][1], acc[h][2], acc[h][3]);
    }
    __syncthreads();

    const int hf = tid * 2;
    const int h = tid >> 6;                     // == hf>>7
    const float l = s_scr[h] + s_scr[4 + h] + s_scr[8 + h] + s_scr[12 + h];
    const float invl = 1.0f / l;
    float v0 = 0.0f, v1 = 0.0f;
#pragma unroll
    for (int w = 0; w < 4; ++w) {
        v0 += s_red[w * 512 + hf];
        v1 += s_red[w * 512 + hf + 1];
    }
    f32x2 o;
    o.x = tanh_fast(v0 * invl);
    o.y = tanh_fast(v1 * invl);
    __builtin_nontemporal_store(o, (f32x2*)&out[(size_t)row * 512 + hf]);
}

// ---------------- Fallback kernel (round-3 version, reads A directly) ----------------
__global__ __launch_bounds__(256, 6) void gat_main_fb(const float* __restrict__ X,
                                                      const float* __restrict__ A,
                                                      const float* __restrict__ aSt,
                                                      const float* __restrict__ aNt,
                                                      const float* __restrict__ gmax,
                                                      float* __restrict__ out) {
    const int tid = threadIdx.x;
    const int bid = blockIdx.x;
    const int row = ((bid & 7) << 11) | (bid >> 3);
    const int b = row >> 11;
    const int lane = tid & 63;
    const int wv = tid >> 6;

    __shared__ short  s_idx[N_NODES];
    __shared__ float4 s_p4[256];
    __shared__ int    s_off[256];
    __shared__ float  s_red[4 * 512];
    __shared__ int    s_wtot[4];
    __shared__ float  s_M[4];
    __shared__ float  s_sv[4];
    __shared__ float  s_scr[16];

    const f32x4* Arow = (const f32x4*)(A + (size_t)row * N_NODES);
    const f32x4 a0 = __builtin_nontemporal_load(Arow + tid * 2);
    const f32x4 a1 = __builtin_nontemporal_load(Arow + tid * 2 + 1);

    if (tid < 4) {
        const float sv = aSt[(size_t)row * 4 + tid];
        const float g = gmax[b * 4 + tid];
        float v = sv + g;
        v = fmaxf(v, LEAKY * v);
        s_M[tid] = v;
        s_sv[tid] = sv;
    }

    const float av[8] = {a0.x, a0.y, a0.z, a0.w, a1.x, a1.y, a1.z, a1.w};
    int c = 0;
#pragma unroll
    for (int k = 0; k < 8; ++k) c += (av[k] != 0.0f) ? 1 : 0;

    int incl = c;
#pragma unroll
    for (int d = 1; d < 64; d <<= 1) {
        const int u = __shfl_up(incl, d);
        if (lane >= d) incl += u;
    }
    if (lane == 63) s_wtot[wv] = incl;
    __syncthreads();
    int wbase = 0;
#pragma unroll
    for (int w = 0; w < 4; ++w) wbase += (w < wv) ? s_wtot[w] : 0;
    const int cnt = s_wtot[0] + s_wtot[1] + s_wtot[2] + s_wtot[3];
    int pos = wbase + (incl - c);
#pragma unroll
    for (int k = 0; k < 8; ++k) {
        if (av[k] != 0.0f) s_idx[pos++] = (short)(tid * 8 + k);
    }
    __syncthreads();

    float acc[4][4];
#pragma unroll
    for (int h = 0; h < 4; ++h)
#pragma unroll
        for (int fi = 0; fi < 4; ++fi) acc[h][fi] = 0.0f;
    float lsum[4] = {0.0f, 0.0f, 0.0f, 0.0f};

    const int jsub = tid >> 5;
    const int f4 = tid & 31;
    const char* XbB = (const char*)(X + (size_t)b * N_NODES * F_DIM) + (f4 << 4);
    const float4* aNb4 = (const float4*)aNt + (size_t)b * N_NODES;

    for (int base = 0; base < cnt; base += 256) {
        const int clen = min(256, cnt - base);
        if (tid < clen) {
            const int m = s_idx[base + tid];
            const float4 t = aNb4[m];
            const float tv[4] = {t.x, t.y, t.z, t.w};
            float4 p4;
            float* pp = (float*)&p4;
#pragma unroll
            for (int h = 0; h < H_HEADS; ++h) {
                float v = s_sv[h] + tv[h];
                v = fmaxf(v, LEAKY * v);
                const float p = __expf(v - s_M[h]);
                pp[h] = p;
                lsum[h] += p;
            }
            s_p4[tid] = p4;
            s_off[tid] = m << 9;
        }
        __syncthreads();
#pragma unroll 4
        for (int j = jsub; j < clen; j += 8) {
            const float4 pv = s_p4[j];
            const float4 xv = *(const float4*)(XbB + (unsigned)s_off[j]);
            FMA16(pv, xv);
        }
        __syncthreads();
    }

#pragma unroll
    for (int h = 0; h < H_HEADS; ++h) {
        float v = lsum[h];
#pragma unroll
        for (int off = 32; off > 0; off >>= 1) v += __shfl_xor(v, off);
        if (lane == 0) s_scr[wv * 4 + h] = v;
    }
#pragma unroll
    for (int h = 0; h < 4; ++h)
#pragma unroll
        for (int fi = 0; fi < 4; ++fi)
            acc[h][fi] += __shfl_xor(acc[h][fi], 32);
    if (lane < 32) {
        float4* red4 = (float4*)s_red;
#pragma unroll
        for (int h = 0; h < 4; ++h)
            red4[wv * 128 + h * 32 + f4] =
                make_float4(acc[h][0], acc[h][1], acc[h][2], acc[h][3]);
    }
    __syncthreads();

    const int hf = tid * 2;
    const int h = tid >> 6;
    const float l = s_scr[h] + s_scr[4 + h] + s_scr[8 + h] + s_scr[12 + h];
    const float invl = 1.0f / l;
    float v0 = 0.0f, v1 = 0.0f;
#pragma unroll
    for (int w = 0; w < 4; ++w) {
        v0 += s_red[w * 512 + hf];
        v1 += s_red[w * 512 + hf + 1];
    }
    f32x2 o;
    o.x = tanh_fast(v0 * invl);
    o.y = tanh_fast(v1 * invl);
    __builtin_nontemporal_store(o, (f32x2*)&out[(size_t)row * 512 + hf]);
}

extern "C" void kernel_launch(void* const* d_in, const int* in_sizes, int n_in,
                              void* d_out, int out_size, void* d_ws, size_t ws_size,
                              hipStream_t stream) {
    const float* X  = (const float*)d_in[0];
    const float* A  = (const float*)d_in[1];
    const float* wS = (const float*)d_in[2];
    const float* wN = (const float*)d_in[3];
    float* out = (float*)d_out;

    float* aSt = (float*)d_ws;                                  // B*N*H floats (packed)
    float* aNt = aSt + (size_t)B_BATCH * N_NODES * H_HEADS;     // B*N*H floats
    float* gmx = aNt + (size_t)B_BATCH * N_NODES * H_HEADS;     // B*H floats
    unsigned char* maskb = (unsigned char*)(gmx + B_BATCH * H_HEADS);

    const size_t need = ((size_t)B_BATCH * N_NODES * H_HEADS * 2 + B_BATCH * H_HEADS) * 4
                        + (size_t)B_BATCH * N_NODES * (N_NODES / 8);

    gat_proj<<<(B_BATCH * N_NODES) / 4, 256, 0, stream>>>(X, wS, wN, aSt, aNt);
    gat_gmax<<<B_BATCH, 256, 0, stream>>>(aNt, gmx);
    if (ws_size >= need) {
        gat_bitpack<<<B_BATCH * N_NODES, 256, 0, stream>>>(A, maskb);
        gat_main<<<B_BATCH * N_NODES, 256, 0, stream>>>(X, (const unsigned*)maskb,
                                                        aSt, aNt, gmx, out);
    } else {
        gat_main_fb<<<B_BATCH * N_NODES, 256, 0, stream>>>(X, A, aSt, aNt, gmx, out);
    }
}

// Round 7
// 129.797 us; speedup vs baseline: 1.3184x; 1.3184x over previous
//
#include <hip/hip_runtime.h>
#include <hip/hip_bf16.h>
#include <math.h>

#define N_NODES 2048
#define F_DIM   128
#define H_HEADS 4
#define B_BATCH 8
#define LEAKY   0.2f

typedef float f32x4 __attribute__((ext_vector_type(4)));
typedef float f32x2 __attribute__((ext_vector_type(2)));

__device__ __forceinline__ float tanh_fast(float x) {
    const float e = __expf(2.0f * x);
    return 1.0f - 2.0f / (e + 1.0f);
}

// ---------------- Kernel 1: projections, packed [b][n][h] ----------------
__global__ __launch_bounds__(256) void gat_proj(const float* __restrict__ X,
                                                const float* __restrict__ wS,
                                                const float* __restrict__ wN,
                                                float* __restrict__ aSt,
                                                float* __restrict__ aNt) {
    const int wave = threadIdx.x >> 6;
    const int lane = threadIdx.x & 63;
    const int row  = blockIdx.x * 4 + wave;            // b*N + n
    const float* xr = X + (size_t)row * F_DIM;
    const float x0 = xr[lane];
    const float x1 = xr[lane + 64];
    float4 ps4, pn4;
    float* psv = (float*)&ps4;
    float* pnv = (float*)&pn4;
#pragma unroll
    for (int h = 0; h < H_HEADS; ++h) {
        float ps = x0 * wS[h * F_DIM + lane] + x1 * wS[h * F_DIM + 64 + lane];
        float pn = x0 * wN[h * F_DIM + lane] + x1 * wN[h * F_DIM + 64 + lane];
#pragma unroll
        for (int off = 32; off > 0; off >>= 1) {
            ps += __shfl_xor(ps, off);
            pn += __shfl_xor(pn, off);
        }
        psv[h] = ps;
        pnv[h] = pn;
    }
    if (lane == 0) {
        ((float4*)aSt)[row] = ps4;
        ((float4*)aNt)[row] = pn4;
    }
}

// ---------------- Kernel 1b: per-(b,h) global max of a_neigh ----------------
__global__ __launch_bounds__(256) void gat_gmax(const float* __restrict__ aNt,
                                                float* __restrict__ gmax) {
    const int b = blockIdx.x;
    const int tid = threadIdx.x;
    const int lane = tid & 63;
    const int wv = tid >> 6;
    __shared__ float4 s_part[4];
    float4 m = make_float4(-1e30f, -1e30f, -1e30f, -1e30f);
    const float4* src = (const float4*)aNt + (size_t)b * N_NODES;
    for (int n = tid; n < N_NODES; n += 256) {
        const float4 v = src[n];
        m.x = fmaxf(m.x, v.x); m.y = fmaxf(m.y, v.y);
        m.z = fmaxf(m.z, v.z); m.w = fmaxf(m.w, v.w);
    }
#pragma unroll
    for (int off = 32; off > 0; off >>= 1) {
        m.x = fmaxf(m.x, __shfl_xor(m.x, off));
        m.y = fmaxf(m.y, __shfl_xor(m.y, off));
        m.z = fmaxf(m.z, __shfl_xor(m.z, off));
        m.w = fmaxf(m.w, __shfl_xor(m.w, off));
    }
    if (lane == 0) s_part[wv] = m;
    __syncthreads();
    if (tid == 0) {
        float4 r = s_part[0];
#pragma unroll
        for (int w = 1; w < 4; ++w) {
            r.x = fmaxf(r.x, s_part[w].x); r.y = fmaxf(r.y, s_part[w].y);
            r.z = fmaxf(r.z, s_part[w].z); r.w = fmaxf(r.w, s_part[w].w);
        }
        ((float4*)gmax)[b] = r;
    }
}

// 32-FMA microtile: 4 heads x 8 feature floats (two float4 halves)
#define FMA32(PV, XL, XH)                                    \
    do {                                                     \
        acc[0][0] = fmaf((PV).x, (XL).x, acc[0][0]);         \
        acc[0][1] = fmaf((PV).x, (XL).y, acc[0][1]);         \
        acc[0][2] = fmaf((PV).x, (XL).z, acc[0][2]);         \
        acc[0][3] = fmaf((PV).x, (XL).w, acc[0][3]);         \
        acc[0][4] = fmaf((PV).x, (XH).x, acc[0][4]);         \
        acc[0][5] = fmaf((PV).x, (XH).y, acc[0][5]);         \
        acc[0][6] = fmaf((PV).x, (XH).z, acc[0][6]);         \
        acc[0][7] = fmaf((PV).x, (XH).w, acc[0][7]);         \
        acc[1][0] = fmaf((PV).y, (XL).x, acc[1][0]);         \
        acc[1][1] = fmaf((PV).y, (XL).y, acc[1][1]);         \
        acc[1][2] = fmaf((PV).y, (XL).z, acc[1][2]);         \
        acc[1][3] = fmaf((PV).y, (XL).w, acc[1][3]);         \
        acc[1][4] = fmaf((PV).y, (XH).x, acc[1][4]);         \
        acc[1][5] = fmaf((PV).y, (XH).y, acc[1][5]);         \
        acc[1][6] = fmaf((PV).y, (XH).z, acc[1][6]);         \
        acc[1][7] = fmaf((PV).y, (XH).w, acc[1][7]);         \
        acc[2][0] = fmaf((PV).z, (XL).x, acc[2][0]);         \
        acc[2][1] = fmaf((PV).z, (XL).y, acc[2][1]);         \
        acc[2][2] = fmaf((PV).z, (XL).z, acc[2][2]);         \
        acc[2][3] = fmaf((PV).z, (XL).w, acc[2][3]);         \
        acc[2][4] = fmaf((PV).z, (XH).x, acc[2][4]);         \
        acc[2][5] = fmaf((PV).z, (XH).y, acc[2][5]);         \
        acc[2][6] = fmaf((PV).z, (XH).z, acc[2][6]);         \
        acc[2][7] = fmaf((PV).z, (XH).w, acc[2][7]);         \
        acc[3][0] = fmaf((PV).w, (XL).x, acc[3][0]);         \
        acc[3][1] = fmaf((PV).w, (XL).y, acc[3][1]);         \
        acc[3][2] = fmaf((PV).w, (XL).z, acc[3][2]);         \
        acc[3][3] = fmaf((PV).w, (XL).w, acc[3][3]);         \
        acc[3][4] = fmaf((PV).w, (XH).x, acc[3][4]);         \
        acc[3][5] = fmaf((PV).w, (XH).y, acc[3][5]);         \
        acc[3][6] = fmaf((PV).w, (XH).z, acc[3][6]);         \
        acc[3][7] = fmaf((PV).w, (XH).w, acc[3][7]);         \
    } while (0)

// ---------------- Kernel 2: sparse softmax-gather per (b,n) row ----------------
// 16 lanes per row (8 floats/thread): half the serial gather chain of the
// 32-lane layout, two independent loads in flight per iteration.
__global__ __launch_bounds__(256, 6) void gat_main(const float* __restrict__ X,
                                                   const float* __restrict__ A,
                                                   const float* __restrict__ aSt,
                                                   const float* __restrict__ aNt,
                                                   const float* __restrict__ gmax,
                                                   float* __restrict__ out) {
    const int tid = threadIdx.x;
    // batch-per-XCD swizzle: XCD k runs exactly batch k (keeps X_b L2-resident).
    const int bid = blockIdx.x;
    const int row = ((bid & 7) << 11) | (bid >> 3);   // b*N + n
    const int b = row >> 11;
    const int lane = tid & 63;
    const int wv = tid >> 6;

    __shared__ short  s_idx[N_NODES];           // compacted neighbor indices (sorted)
    __shared__ float4 s_p4[256];                // p for chunk: [entry][head]
    __shared__ int    s_off[256];               // X-row byte offsets for chunk
    __shared__ float  s_red[4 * 512];           // per-wave partial sums
    __shared__ int    s_wtot[4];
    __shared__ float  s_M[4];
    __shared__ float  s_sv[4];
    __shared__ float  s_scr[16];                // [wv][h] lsum partials

    // ---- Phase 1: scan A row (nt: zero reuse, don't evict X from L2) ----
    const f32x4* Arow = (const f32x4*)(A + (size_t)row * N_NODES);
    const f32x4 a0 = __builtin_nontemporal_load(Arow + tid * 2);
    const f32x4 a1 = __builtin_nontemporal_load(Arow + tid * 2 + 1);

    if (tid < 4) {                              // per-head constants
        const float sv = aSt[(size_t)row * 4 + tid];
        const float g = gmax[b * 4 + tid];
        float v = sv + g;
        v = fmaxf(v, LEAKY * v);                // leaky, monotonic -> valid upper bound
        s_M[tid] = v;
        s_sv[tid] = sv;
    }

    const float av[8] = {a0.x, a0.y, a0.z, a0.w, a1.x, a1.y, a1.z, a1.w};
    int c = 0;
#pragma unroll
    for (int k = 0; k < 8; ++k) c += (av[k] != 0.0f) ? 1 : 0;

    int incl = c;
#pragma unroll
    for (int d = 1; d < 64; d <<= 1) {
        const int u = __shfl_up(incl, d);
        if (lane >= d) incl += u;
    }
    if (lane == 63) s_wtot[wv] = incl;
    __syncthreads();
    int wbase = 0;
#pragma unroll
    for (int w = 0; w < 4; ++w) wbase += (w < wv) ? s_wtot[w] : 0;
    const int cnt = s_wtot[0] + s_wtot[1] + s_wtot[2] + s_wtot[3];
    int pos = wbase + (incl - c);
#pragma unroll
    for (int k = 0; k < 8; ++k) {
        if (av[k] != 0.0f) s_idx[pos++] = (short)(tid * 8 + k);
    }
    __syncthreads();

    // hoist per-head constants into registers (barrier blocks LDS hoisting)
    const float rsv[4] = {s_sv[0], s_sv[1], s_sv[2], s_sv[3]};
    const float rM[4]  = {s_M[0], s_M[1], s_M[2], s_M[3]};

    // ---- Phase 2: chunked p-generation + gather-accumulate ----
    float acc[4][8];
#pragma unroll
    for (int h = 0; h < 4; ++h)
#pragma unroll
        for (int fi = 0; fi < 8; ++fi) acc[h][fi] = 0.0f;
    float lsum[4] = {0.0f, 0.0f, 0.0f, 0.0f};

    const int j16 = tid >> 4;                   // 0..15: row subgroup
    const int f8 = tid & 15;                    // 0..15: feature block (8 floats)
    const char* XbB = (const char*)(X + (size_t)b * N_NODES * F_DIM) + (f8 << 5);
    const float4* aNb4 = (const float4*)aNt + (size_t)b * N_NODES;

    for (int base = 0; base < cnt; base += 256) {
        const int clen = min(256, cnt - base);
        const int plen = (clen + 15) & ~15;     // pad to multiple of 16
        float4 p4 = make_float4(0.0f, 0.0f, 0.0f, 0.0f);
        int offv = 0;
        if (tid < clen) {
            const int m = s_idx[base + tid];
            const float4 t = aNb4[m];
            const float tv[4] = {t.x, t.y, t.z, t.w};
            float* pp = (float*)&p4;
#pragma unroll
            for (int h = 0; h < H_HEADS; ++h) {
                float v = rsv[h] + tv[h];
                v = fmaxf(v, LEAKY * v);
                const float p = __expf(v - rM[h]);
                pp[h] = p;
                lsum[h] += p;
            }
            offv = m << 9;                      // byte offset of X row
        }
        s_p4[tid] = p4;                         // zeros beyond clen (covers padding)
        s_off[tid] = offv;
        __syncthreads();

        for (int j = j16; j < plen; j += 16) {
            const float4 pv = s_p4[j];
            const char* bp = XbB + (unsigned)s_off[j];
            const float4 xlo = *(const float4*)bp;
            const float4 xhi = *(const float4*)(bp + 16);
            FMA32(pv, xlo, xhi);
        }
        __syncthreads();
    }

    // ---- Phase 3: reductions + output ----
#pragma unroll
    for (int h = 0; h < H_HEADS; ++h) {
        float v = lsum[h];
#pragma unroll
        for (int off = 32; off > 0; off >>= 1) v += __shfl_xor(v, off);
        if (lane == 0) s_scr[wv * 4 + h] = v;
    }
    // reduce the wave's 4 row-subgroups (lane^16, lane^32 preserve f8)
#pragma unroll
    for (int h = 0; h < 4; ++h)
#pragma unroll
        for (int fi = 0; fi < 8; ++fi) {
            acc[h][fi] += __shfl_xor(acc[h][fi], 16);
            acc[h][fi] += __shfl_xor(acc[h][fi], 32);
        }
    if (lane < 16) {
        float* rb = s_red + wv * 512 + f8 * 8;  // feature = f8*8 + fi
#pragma unroll
        for (int h = 0; h < 4; ++h) {
            *(float4*)(rb + h * 128)     = make_float4(acc[h][0], acc[h][1], acc[h][2], acc[h][3]);
            *(float4*)(rb + h * 128 + 4) = make_float4(acc[h][4], acc[h][5], acc[h][6], acc[h][7]);
        }
    }
    __syncthreads();

    const int hf = tid * 2;
    const int h = tid >> 6;                     // == hf>>7
    const float l = s_scr[h] + s_scr[4 + h] + s_scr[8 + h] + s_scr[12 + h];
    const float invl = 1.0f / l;
    float v0 = 0.0f, v1 = 0.0f;
#pragma unroll
    for (int w = 0; w < 4; ++w) {
        v0 += s_red[w * 512 + hf];
        v1 += s_red[w * 512 + hf + 1];
    }
    f32x2 o;
    o.x = tanh_fast(v0 * invl);
    o.y = tanh_fast(v1 * invl);
    __builtin_nontemporal_store(o, (f32x2*)&out[(size_t)row * 512 + hf]);
}

extern "C" void kernel_launch(void* const* d_in, const int* in_sizes, int n_in,
                              void* d_out, int out_size, void* d_ws, size_t ws_size,
                              hipStream_t stream) {
    const float* X  = (const float*)d_in[0];
    const float* A  = (const float*)d_in[1];
    const float* wS = (const float*)d_in[2];
    const float* wN = (const float*)d_in[3];
    float* out = (float*)d_out;

    float* aSt = (float*)d_ws;                                  // B*N*H floats (packed)
    float* aNt = aSt + (size_t)B_BATCH * N_NODES * H_HEADS;     // B*N*H floats
    float* gmx = aNt + (size_t)B_BATCH * N_NODES * H_HEADS;     // B*H floats

    gat_proj<<<(B_BATCH * N_NODES) / 4, 256, 0, stream>>>(X, wS, wN, aSt, aNt);
    gat_gmax<<<B_BATCH, 256, 0, stream>>>(aNt, gmx);
    gat_main<<<B_BATCH * N_NODES, 256, 0, stream>>>(X, A, aSt, aNt, gmx, out);
}

// Round 8
// 129.008 us; speedup vs baseline: 1.3265x; 1.0061x over previous
//
#include <hip/hip_runtime.h>
#include <hip/hip_bf16.h>
#include <math.h>

#define N_NODES 2048
#define F_DIM   128
#define H_HEADS 4
#define B_BATCH 8
#define LEAKY   0.2f

typedef float f32x4 __attribute__((ext_vector_type(4)));
typedef float f32x2 __attribute__((ext_vector_type(2)));

__device__ __forceinline__ float tanh_fast(float x) {
    const float e = __expf(2.0f * x);
    return 1.0f - 2.0f / (e + 1.0f);
}

// ---------------- Kernel 1: projections, packed [b][n][h] ----------------
__global__ __launch_bounds__(256) void gat_proj(const float* __restrict__ X,
                                                const float* __restrict__ wS,
                                                const float* __restrict__ wN,
                                                float* __restrict__ aSt,
                                                float* __restrict__ aNt) {
    const int wave = threadIdx.x >> 6;
    const int lane = threadIdx.x & 63;
    const int row  = blockIdx.x * 4 + wave;            // b*N + n
    const float* xr = X + (size_t)row * F_DIM;
    const float x0 = xr[lane];
    const float x1 = xr[lane + 64];
    float4 ps4, pn4;
    float* psv = (float*)&ps4;
    float* pnv = (float*)&pn4;
#pragma unroll
    for (int h = 0; h < H_HEADS; ++h) {
        float ps = x0 * wS[h * F_DIM + lane] + x1 * wS[h * F_DIM + 64 + lane];
        float pn = x0 * wN[h * F_DIM + lane] + x1 * wN[h * F_DIM + 64 + lane];
#pragma unroll
        for (int off = 32; off > 0; off >>= 1) {
            ps += __shfl_xor(ps, off);
            pn += __shfl_xor(pn, off);
        }
        psv[h] = ps;
        pnv[h] = pn;
    }
    if (lane == 0) {
        ((float4*)aSt)[row] = ps4;
        ((float4*)aNt)[row] = pn4;
    }
}

// ---------------- Kernel 1b: per-(b,h) global max of a_neigh ----------------
__global__ __launch_bounds__(256) void gat_gmax(const float* __restrict__ aNt,
                                                float* __restrict__ gmax) {
    const int b = blockIdx.x;
    const int tid = threadIdx.x;
    const int lane = tid & 63;
    const int wv = tid >> 6;
    __shared__ float4 s_part[4];
    float4 m = make_float4(-1e30f, -1e30f, -1e30f, -1e30f);
    const float4* src = (const float4*)aNt + (size_t)b * N_NODES;
    for (int n = tid; n < N_NODES; n += 256) {
        const float4 v = src[n];
        m.x = fmaxf(m.x, v.x); m.y = fmaxf(m.y, v.y);
        m.z = fmaxf(m.z, v.z); m.w = fmaxf(m.w, v.w);
    }
#pragma unroll
    for (int off = 32; off > 0; off >>= 1) {
        m.x = fmaxf(m.x, __shfl_xor(m.x, off));
        m.y = fmaxf(m.y, __shfl_xor(m.y, off));
        m.z = fmaxf(m.z, __shfl_xor(m.z, off));
        m.w = fmaxf(m.w, __shfl_xor(m.w, off));
    }
    if (lane == 0) s_part[wv] = m;
    __syncthreads();
    if (tid == 0) {
        float4 r = s_part[0];
#pragma unroll
        for (int w = 1; w < 4; ++w) {
            r.x = fmaxf(r.x, s_part[w].x); r.y = fmaxf(r.y, s_part[w].y);
            r.z = fmaxf(r.z, s_part[w].z); r.w = fmaxf(r.w, s_part[w].w);
        }
        ((float4*)gmax)[b] = r;
    }
}

// 32-FMA microtile: 4 heads x 8 feature floats (two contiguous half-rows)
#define FMA32(PV, XL, XH)                                    \
    do {                                                     \
        acc[0][0] = fmaf((PV).x, (XL).x, acc[0][0]);         \
        acc[0][1] = fmaf((PV).x, (XL).y, acc[0][1]);         \
        acc[0][2] = fmaf((PV).x, (XL).z, acc[0][2]);         \
        acc[0][3] = fmaf((PV).x, (XL).w, acc[0][3]);         \
        acc[0][4] = fmaf((PV).x, (XH).x, acc[0][4]);         \
        acc[0][5] = fmaf((PV).x, (XH).y, acc[0][5]);         \
        acc[0][6] = fmaf((PV).x, (XH).z, acc[0][6]);         \
        acc[0][7] = fmaf((PV).x, (XH).w, acc[0][7]);         \
        acc[1][0] = fmaf((PV).y, (XL).x, acc[1][0]);         \
        acc[1][1] = fmaf((PV).y, (XL).y, acc[1][1]);         \
        acc[1][2] = fmaf((PV).y, (XL).z, acc[1][2]);         \
        acc[1][3] = fmaf((PV).y, (XL).w, acc[1][3]);         \
        acc[1][4] = fmaf((PV).y, (XH).x, acc[1][4]);         \
        acc[1][5] = fmaf((PV).y, (XH).y, acc[1][5]);         \
        acc[1][6] = fmaf((PV).y, (XH).z, acc[1][6]);         \
        acc[1][7] = fmaf((PV).y, (XH).w, acc[1][7]);         \
        acc[2][0] = fmaf((PV).z, (XL).x, acc[2][0]);         \
        acc[2][1] = fmaf((PV).z, (XL).y, acc[2][1]);         \
        acc[2][2] = fmaf((PV).z, (XL).z, acc[2][2]);         \
        acc[2][3] = fmaf((PV).z, (XL).w, acc[2][3]);         \
        acc[2][4] = fmaf((PV).z, (XH).x, acc[2][4]);         \
        acc[2][5] = fmaf((PV).z, (XH).y, acc[2][5]);         \
        acc[2][6] = fmaf((PV).z, (XH).z, acc[2][6]);         \
        acc[2][7] = fmaf((PV).z, (XH).w, acc[2][7]);         \
        acc[3][0] = fmaf((PV).w, (XL).x, acc[3][0]);         \
        acc[3][1] = fmaf((PV).w, (XL).y, acc[3][1]);         \
        acc[3][2] = fmaf((PV).w, (XL).z, acc[3][2]);         \
        acc[3][3] = fmaf((PV).w, (XL).w, acc[3][3]);         \
        acc[3][4] = fmaf((PV).w, (XH).x, acc[3][4]);         \
        acc[3][5] = fmaf((PV).w, (XH).y, acc[3][5]);         \
        acc[3][6] = fmaf((PV).w, (XH).z, acc[3][6]);         \
        acc[3][7] = fmaf((PV).w, (XH).w, acc[3][7]);         \
    } while (0)

// ---------------- Kernel 2: sparse softmax-gather per (b,n) row ----------------
// 16 lanes per row, 8 floats/thread as TWO CONTIGUOUS HALF-ROWS:
//   xlo = row[f8*16 .. +16)          (16 lanes -> contiguous 256 B)
//   xhi = row[256 + f8*16 .. +16)    (16 lanes -> contiguous 256 B)
// Half the serial gather chain of the 32-lane layout, full coalescing.
__global__ __launch_bounds__(256, 6) void gat_main(const float* __restrict__ X,
                                                   const float* __restrict__ A,
                                                   const float* __restrict__ aSt,
                                                   const float* __restrict__ aNt,
                                                   const float* __restrict__ gmax,
                                                   float* __restrict__ out) {
    const int tid = threadIdx.x;
    // batch-per-XCD swizzle: XCD k runs exactly batch k (keeps X_b L2-resident).
    const int bid = blockIdx.x;
    const int row = ((bid & 7) << 11) | (bid >> 3);   // b*N + n
    const int b = row >> 11;
    const int lane = tid & 63;
    const int wv = tid >> 6;

    __shared__ short  s_idx[N_NODES];           // compacted neighbor indices (sorted)
    __shared__ float4 s_p4[256];                // p for chunk: [entry][head]
    __shared__ int    s_off[256];               // X-row byte offsets for chunk
    __shared__ float  s_red[4 * 512];           // per-wave partial sums
    __shared__ int    s_wtot[4];
    __shared__ float  s_M[4];
    __shared__ float  s_sv[4];
    __shared__ float  s_scr[16];                // [wv][h] lsum partials

    // ---- Phase 1: scan A row (nt: zero reuse, don't evict X from L2) ----
    const f32x4* Arow = (const f32x4*)(A + (size_t)row * N_NODES);
    const f32x4 a0 = __builtin_nontemporal_load(Arow + tid * 2);
    const f32x4 a1 = __builtin_nontemporal_load(Arow + tid * 2 + 1);

    if (tid < 4) {                              // per-head constants
        const float sv = aSt[(size_t)row * 4 + tid];
        const float g = gmax[b * 4 + tid];
        float v = sv + g;
        v = fmaxf(v, LEAKY * v);                // leaky, monotonic -> valid upper bound
        s_M[tid] = v;
        s_sv[tid] = sv;
    }

    const float av[8] = {a0.x, a0.y, a0.z, a0.w, a1.x, a1.y, a1.z, a1.w};
    int c = 0;
#pragma unroll
    for (int k = 0; k < 8; ++k) c += (av[k] != 0.0f) ? 1 : 0;

    int incl = c;
#pragma unroll
    for (int d = 1; d < 64; d <<= 1) {
        const int u = __shfl_up(incl, d);
        if (lane >= d) incl += u;
    }
    if (lane == 63) s_wtot[wv] = incl;
    __syncthreads();
    int wbase = 0;
#pragma unroll
    for (int w = 0; w < 4; ++w) wbase += (w < wv) ? s_wtot[w] : 0;
    const int cnt = s_wtot[0] + s_wtot[1] + s_wtot[2] + s_wtot[3];
    int pos = wbase + (incl - c);
#pragma unroll
    for (int k = 0; k < 8; ++k) {
        if (av[k] != 0.0f) s_idx[pos++] = (short)(tid * 8 + k);
    }
    __syncthreads();

    // hoist per-head constants into registers (barrier blocks LDS hoisting)
    const float rsv[4] = {s_sv[0], s_sv[1], s_sv[2], s_sv[3]};
    const float rM[4]  = {s_M[0], s_M[1], s_M[2], s_M[3]};

    // ---- Phase 2: chunked p-generation + gather-accumulate ----
    float acc[4][8];
#pragma unroll
    for (int h = 0; h < 4; ++h)
#pragma unroll
        for (int fi = 0; fi < 8; ++fi) acc[h][fi] = 0.0f;
    float lsum[4] = {0.0f, 0.0f, 0.0f, 0.0f};

    const int j16 = tid >> 4;                   // 0..15: row subgroup
    const int f8 = tid & 15;                    // 0..15: feature sub-block
    const char* XbB = (const char*)(X + (size_t)b * N_NODES * F_DIM) + (f8 << 4);
    const float4* aNb4 = (const float4*)aNt + (size_t)b * N_NODES;

    for (int base = 0; base < cnt; base += 256) {
        const int clen = min(256, cnt - base);
        const int plen = (clen + 15) & ~15;     // pad to multiple of 16
        float4 p4 = make_float4(0.0f, 0.0f, 0.0f, 0.0f);
        int offv = 0;
        if (tid < clen) {
            const int m = s_idx[base + tid];
            const float4 t = aNb4[m];
            const float tv[4] = {t.x, t.y, t.z, t.w};
            float* pp = (float*)&p4;
#pragma unroll
            for (int h = 0; h < H_HEADS; ++h) {
                float v = rsv[h] + tv[h];
                v = fmaxf(v, LEAKY * v);
                const float p = __expf(v - rM[h]);
                pp[h] = p;
                lsum[h] += p;
            }
            offv = m << 9;                      // byte offset of X row
        }
        s_p4[tid] = p4;                         // zeros beyond clen (covers padding)
        s_off[tid] = offv;
        __syncthreads();

        for (int j = j16; j < plen; j += 16) {
            const float4 pv = s_p4[j];
            const char* bp = XbB + (unsigned)s_off[j];
            const float4 xlo = *(const float4*)bp;          // first half-row
            const float4 xhi = *(const float4*)(bp + 256);  // second half-row
            FMA32(pv, xlo, xhi);
        }
        __syncthreads();
    }

    // ---- Phase 3: reductions + output ----
#pragma unroll
    for (int h = 0; h < H_HEADS; ++h) {
        float v = lsum[h];
#pragma unroll
        for (int off = 32; off > 0; off >>= 1) v += __shfl_xor(v, off);
        if (lane == 0) s_scr[wv * 4 + h] = v;
    }
    // reduce the wave's 4 row-subgroups (lane^16, lane^32 preserve f8)
#pragma unroll
    for (int h = 0; h < 4; ++h)
#pragma unroll
        for (int fi = 0; fi < 8; ++fi) {
            acc[h][fi] += __shfl_xor(acc[h][fi], 16);
            acc[h][fi] += __shfl_xor(acc[h][fi], 32);
        }
    if (lane < 16) {
        // features: lo half = f8*4+fi, hi half = 64 + f8*4+fi
        float* rb = s_red + wv * 512 + f8 * 4;  // 16 B lane stride: 2-way alias, free
#pragma unroll
        for (int h = 0; h < 4; ++h) {
            *(float4*)(rb + h * 128)      = make_float4(acc[h][0], acc[h][1], acc[h][2], acc[h][3]);
            *(float4*)(rb + h * 128 + 64) = make_float4(acc[h][4], acc[h][5], acc[h][6], acc[h][7]);
        }
    }
    __syncthreads();

    const int hf = tid * 2;
    const int h = tid >> 6;                     // == hf>>7
    const float l = s_scr[h] + s_scr[4 + h] + s_scr[8 + h] + s_scr[12 + h];
    const float invl = 1.0f / l;
    float v0 = 0.0f, v1 = 0.0f;
#pragma unroll
    for (int w = 0; w < 4; ++w) {
        v0 += s_red[w * 512 + hf];
        v1 += s_red[w * 512 + hf + 1];
    }
    f32x2 o;
    o.x = tanh_fast(v0 * invl);
    o.y = tanh_fast(v1 * invl);
    __builtin_nontemporal_store(o, (f32x2*)&out[(size_t)row * 512 + hf]);
}

extern "C" void kernel_launch(void* const* d_in, const int* in_sizes, int n_in,
                              void* d_out, int out_size, void* d_ws, size_t ws_size,
                              hipStream_t stream) {
    const float* X  = (const float*)d_in[0];
    const float* A  = (const float*)d_in[1];
    const float* wS = (const float*)d_in[2];
    const float* wN = (const float*)d_in[3];
    float* out = (float*)d_out;

    float* aSt = (float*)d_ws;                                  // B*N*H floats (packed)
    float* aNt = aSt + (size_t)B_BATCH * N_NODES * H_HEADS;     // B*N*H floats
    float* gmx = aNt + (size_t)B_BATCH * N_NODES * H_HEADS;     // B*H floats

    gat_proj<<<(B_BATCH * N_NODES) / 4, 256, 0, stream>>>(X, wS, wN, aSt, aNt);
    gat_gmax<<<B_BATCH, 256, 0, stream>>>(aNt, gmx);
    gat_main<<<B_BATCH * N_NODES, 256, 0, stream>>>(X, A, aSt, aNt, gmx, out);
}